// Round 2
// baseline (649.641 us; speedup 1.0000x reference)
//
#include <hip/hip_runtime.h>

// B=8, S=2048, D=1024, U=1024, fp32 in/out, bf16-grade tolerance.
// Pipeline (bf16 MFMA TN GEMMs):
//   WqmT = metricT @ WqB            (metric folded into Wq)
//   Qb   = X1b @ WqmT + bqm  -> d_out[0:33.5MB]     (scratch in d_out!)
//   Kb   = X2b @ WkT  + bk   -> d_out[33.5:67MB]
//   Vt_b = WvT @ X2b_b^T + bv  [U][S] per batch
//   Sc_b = Qb_b @ Kb_b^T  bf16, aliased over X1b+X2b (dead), causal tile skip
//   alpha = softmax(Sc/32) bf16 in place
//   Out_b = alpha_b @ Vt_b^T -> d_out (fp32), causal K-limit
// Peak d_ws: Vt(33.5MB) + weights(10.5MB) + Sc-alias(67MB) = 111,153,152 B.

#define Bq 8
#define Sq 2048
#define Dq 1024
#define Uq 1024

typedef __bf16 bf16;
typedef __bf16 bf16x8 __attribute__((ext_vector_type(8)));
typedef float f32x4 __attribute__((ext_vector_type(4)));
typedef unsigned short u16;
typedef unsigned int u32;

__device__ __forceinline__ u16 f2bf(float f) {
  u32 u = __builtin_bit_cast(u32, f);
  u32 r = u + 0x7fffu + ((u >> 16) & 1u);
  return (u16)(r >> 16);
}
__device__ __forceinline__ float bf2f(u32 h) {
  return __builtin_bit_cast(float, h << 16);
}

__device__ __forceinline__ void gl_lds16(const void* g, void* l) {
  __builtin_amdgcn_global_load_lds(
      (const __attribute__((address_space(1))) u32*)g,
      (__attribute__((address_space(3))) u32*)l, 16, 0, 0);
}

// ---------------- converts ----------------

__global__ __launch_bounds__(256) void cvt_bf16(const float* __restrict__ in,
                                                u16* __restrict__ out, int n4) {
  int idx = blockIdx.x * 256 + threadIdx.x;
  if (idx >= n4) return;
  float4 v = ((const float4*)in)[idx];
  ushort4 o;
  o.x = f2bf(v.x); o.y = f2bf(v.y); o.z = f2bf(v.z); o.w = f2bf(v.w);
  ((ushort4*)out)[idx] = o;
}

// out[x][y] = bf16(in[y][x]), N x N
__global__ __launch_bounds__(256) void transpose_cvt(const float* __restrict__ in,
                                                     u16* __restrict__ out, int N) {
  __shared__ float tile[32][33];
  int tx = threadIdx.x & 31, ty = threadIdx.x >> 5;  // 32 x 8
  int x0 = blockIdx.x * 32, y0 = blockIdx.y * 32;
#pragma unroll
  for (int r = 0; r < 32; r += 8)
    tile[ty + r][tx] = in[(size_t)(y0 + ty + r) * N + x0 + tx];
  __syncthreads();
#pragma unroll
  for (int r = 0; r < 32; r += 8)
    out[(size_t)(x0 + ty + r) * N + y0 + tx] = f2bf(tile[tx][ty + r]);
}

__global__ __launch_bounds__(256) void bqm_kernel(const float* __restrict__ bq,
                                                  const float* __restrict__ metric,
                                                  float* __restrict__ bqm) {
  int v = blockIdx.x * 256 + threadIdx.x;
  float s = 0.f;
  for (int u = 0; u < Uq; ++u) s += bq[u] * metric[(size_t)u * Uq + v];
  bqm[v] = s;
}

__global__ __launch_bounds__(256) void fill_zero(float4* __restrict__ p, int n4) {
  int i = blockIdx.x * 256 + threadIdx.x;
  if (i < n4) p[i] = float4{0.f, 0.f, 0.f, 0.f};
}

// ---------------- TN bf16 MFMA GEMM ----------------
// C[m][n] = sum_k A[m*lda+k] * B[n*ldb+k] (+ bias)
// BIAS: 0 none, 1 per-col(n), 2 per-row(m). OUT_BF16: 1 -> u16 bf16 out.
#define BM 128
#define BN 128
#define BK 32

template <int OUT_BF16, int BIAS>
__global__ __launch_bounds__(256) void gemm_tn(
    const bf16* __restrict__ A, const bf16* __restrict__ B, void* __restrict__ Cv,
    const float* __restrict__ bias, int lda, int ldb, int ldc,
    long long sA, long long sB, long long sC, int K,
    int causal_skip, int causal_klimit) {
  __shared__ __align__(16) bf16 lA[BM * BK];
  __shared__ __align__(16) bf16 lB[BN * BK];
  int m0 = blockIdx.x * BM, n0 = blockIdx.y * BN;
  if (causal_skip && n0 > m0 + BM - 1) return;
  long long b = blockIdx.z;
  A += b * sA;
  B += b * sB;
  int t = threadIdx.x;
  int w = t >> 6, l = t & 63;
  int wr = (w >> 1) * 64, wc = (w & 1) * 64;
  int Kend = causal_klimit ? min(K, m0 + BM) : K;
  int nk = Kend / BK;

  f32x4 acc[4][4] = {};
  int rowA = t >> 2, kc = (t & 3) * 8;  // 64B rows, 4 x 16B chunks per row
  char* lAb = (char*)lA + w * 1024;
  char* lBb = (char*)lB + w * 1024;
  int lm = l & 15, q = l >> 4;

  for (int kt = 0; kt < nk; ++kt) {
    int k0 = kt * BK;
    const bf16* ga0 = A + (long long)(m0 + rowA) * lda + k0 + kc;
    const bf16* gb0 = B + (long long)(n0 + rowA) * ldb + k0 + kc;
    gl_lds16(ga0, lAb);
    gl_lds16(ga0 + (long long)64 * lda, lAb + 4096);
    gl_lds16(gb0, lBb);
    gl_lds16(gb0 + (long long)64 * ldb, lBb + 4096);
    __syncthreads();
    bf16x8 af[4], bfr[4];
#pragma unroll
    for (int i = 0; i < 4; ++i)
      af[i] = *(const bf16x8*)&lA[(wr + i * 16 + lm) * BK + q * 8];
#pragma unroll
    for (int i = 0; i < 4; ++i)
      bfr[i] = *(const bf16x8*)&lB[(wc + i * 16 + lm) * BK + q * 8];
#pragma unroll
    for (int i = 0; i < 4; ++i)
#pragma unroll
      for (int j = 0; j < 4; ++j)
        acc[i][j] = __builtin_amdgcn_mfma_f32_16x16x32_bf16(af[i], bfr[j], acc[i][j], 0, 0, 0);
    __syncthreads();
  }

  // epilogue: C row = wr + i*16 + q*4 + r ; col = wc + j*16 + lm
  char* Cb = (char*)Cv + (OUT_BF16 ? b * sC * 2 : b * sC * 4);
#pragma unroll
  for (int i = 0; i < 4; ++i) {
#pragma unroll
    for (int j = 0; j < 4; ++j) {
      int col = n0 + wc + j * 16 + lm;
      float bc = (BIAS == 1) ? bias[col] : 0.f;
#pragma unroll
      for (int r = 0; r < 4; ++r) {
        int row = m0 + wr + i * 16 + q * 4 + r;
        float v = acc[i][j][r] + bc;
        if (BIAS == 2) v += bias[row];
        size_t idx = (size_t)row * ldc + col;
        if (OUT_BF16)
          ((u16*)Cb)[idx] = f2bf(v);
        else
          ((float*)Cb)[idx] = v;
      }
    }
  }
}

// ---------------- causal softmax (bf16 in place) ----------------
// blockIdx.x = b*S + i ; row of 2048 bf16 scores -> 2048 bf16 alpha.
__global__ __launch_bounds__(256) void softmax_causal(u16* __restrict__ sc) {
  __shared__ __align__(16) float sm[Sq];
  __shared__ float red[8];
  int gr = blockIdx.x;
  int i = gr & (Sq - 1);
  u16* rowp = sc + (size_t)gr * Sq;
  int t = threadIdx.x;
  uint4 pk = ((const uint4*)rowp)[t];  // 8 bf16
  float4 lo, hi;
  lo.x = bf2f(pk.x & 0xffffu); lo.y = bf2f(pk.x >> 16);
  lo.z = bf2f(pk.y & 0xffffu); lo.w = bf2f(pk.y >> 16);
  hi.x = bf2f(pk.z & 0xffffu); hi.y = bf2f(pk.z >> 16);
  hi.z = bf2f(pk.w & 0xffffu); hi.w = bf2f(pk.w >> 16);
  ((float4*)sm)[2 * t] = lo;
  ((float4*)sm)[2 * t + 1] = hi;
  __syncthreads();
  int nv = i + 1;
  const float scl = 0.03125f;  // 1/sqrt(U) = 1/32
  float m = -1e30f;
  for (int j = t; j < nv; j += 256) m = fmaxf(m, sm[j]);
#pragma unroll
  for (int o = 32; o; o >>= 1) m = fmaxf(m, __shfl_xor(m, o));
  if ((t & 63) == 0) red[t >> 6] = m;
  __syncthreads();
  m = fmaxf(fmaxf(red[0], red[1]), fmaxf(red[2], red[3])) * scl;
  float sum = 0.f;
  for (int j = t; j < nv; j += 256) sum += __expf(sm[j] * scl - m);
#pragma unroll
  for (int o = 32; o; o >>= 1) sum += __shfl_xor(sum, o);
  if ((t & 63) == 0) red[4 + (t >> 6)] = sum;
  __syncthreads();
  float rinv = 1.0f / (red[4] + red[5] + red[6] + red[7]);
  int j0 = t * 8;
  u16 ov[8];
#pragma unroll
  for (int k = 0; k < 8; ++k)
    ov[k] = (j0 + k < nv) ? f2bf(__expf(sm[j0 + k] * scl - m) * rinv) : (u16)0;
  uint4 po;
  po.x = (u32)ov[0] | ((u32)ov[1] << 16);
  po.y = (u32)ov[2] | ((u32)ov[3] << 16);
  po.z = (u32)ov[4] | ((u32)ov[5] << 16);
  po.w = (u32)ov[6] | ((u32)ov[7] << 16);
  ((uint4*)rowp)[t] = po;
}

// ---------------- launch ----------------

extern "C" void kernel_launch(void* const* d_in, const int* in_sizes, int n_in,
                              void* d_out, int out_size, void* d_ws, size_t ws_size,
                              hipStream_t stream) {
  const float* X1 = (const float*)d_in[0];
  const float* X2 = (const float*)d_in[1];
  const float* Wq = (const float*)d_in[2];
  const float* bq = (const float*)d_in[3];
  const float* Wk = (const float*)d_in[4];
  const float* bk = (const float*)d_in[5];
  const float* Wv = (const float*)d_in[6];
  const float* bv = (const float*)d_in[7];
  const float* metric = (const float*)d_in[8];
  float* out = (float*)d_out;

  const size_t XB = (size_t)Bq * Sq * Dq * 2;  // 33,554,432 B
  const size_t WB = (size_t)Dq * Uq * 2;       // 2,097,152 B
  const size_t NEED = 3 * XB + 5 * WB + 4096;  // 111,153,152 B

  if (ws_size < NEED) {
    // diagnostic fallback: workspace too small — clean numeric failure
    fill_zero<<<(out_size / 4 + 255) / 256, 256, 0, stream>>>((float4*)d_out, out_size / 4);
    return;
  }

  char* ws = (char*)d_ws;
  bf16* X1b = (bf16*)(ws);
  bf16* X2b = (bf16*)(ws + XB);
  bf16* Vt = (bf16*)(ws + 2 * XB);
  bf16* WqB = (bf16*)(ws + 3 * XB);
  bf16* metT = (bf16*)(ws + 3 * XB + WB);
  bf16* WkT = (bf16*)(ws + 3 * XB + 2 * WB);
  bf16* WvT = (bf16*)(ws + 3 * XB + 3 * WB);
  bf16* WqmT = (bf16*)(ws + 3 * XB + 4 * WB);
  float* bqm = (float*)(ws + 3 * XB + 5 * WB);
  u16* Sc = (u16*)ws;  // 67,108,864 B bf16 scores, aliases X1b+X2b (dead by then)
  bf16* Qb = (bf16*)d_out;                          // scratch in d_out
  bf16* Kb = (bf16*)d_out + (size_t)Bq * Sq * Uq;   // second half of d_out

  // converts
  cvt_bf16<<<(Bq * Sq * Dq / 4 + 255) / 256, 256, 0, stream>>>(X1, (u16*)X1b, Bq * Sq * Dq / 4);
  cvt_bf16<<<(Bq * Sq * Dq / 4 + 255) / 256, 256, 0, stream>>>(X2, (u16*)X2b, Bq * Sq * Dq / 4);
  cvt_bf16<<<(Dq * Uq / 4 + 255) / 256, 256, 0, stream>>>(Wq, (u16*)WqB, Dq * Uq / 4);
  dim3 tg(32, 32);
  transpose_cvt<<<tg, 256, 0, stream>>>(metric, (u16*)metT, Uq);
  transpose_cvt<<<tg, 256, 0, stream>>>(Wk, (u16*)WkT, Dq);
  transpose_cvt<<<tg, 256, 0, stream>>>(Wv, (u16*)WvT, Dq);
  bqm_kernel<<<Uq / 256, 256, 0, stream>>>(bq, metric, bqm);

  // WqmT[v][d] = sum_u metT[v][u] * WqB[d][u]
  gemm_tn<1, 0><<<dim3(Uq / BM, Dq / BN, 1), 256, 0, stream>>>(
      metT, WqB, WqmT, nullptr, Uq, Uq, Dq, 0, 0, 0, Uq, 0, 0);

  const int MQ = Bq * Sq;  // 16384
  // Qb = X1b @ WqmT^T + bqm   -> d_out scratch
  gemm_tn<1, 1><<<dim3(MQ / BM, Uq / BN, 1), 256, 0, stream>>>(
      X1b, WqmT, Qb, bqm, Dq, Dq, Uq, 0, 0, 0, Dq, 0, 0);
  // Kb = X2b @ WkT + bk       -> d_out scratch
  gemm_tn<1, 1><<<dim3(MQ / BM, Uq / BN, 1), 256, 0, stream>>>(
      X2b, WkT, Kb, bk, Dq, Dq, Uq, 0, 0, 0, Dq, 0, 0);
  // Vt[b][u][j] = sum_d WvT[u][d] * X2b[b][j][d] + bv[u]
  gemm_tn<1, 2><<<dim3(Uq / BM, Sq / BN, Bq), 256, 0, stream>>>(
      WvT, X2b, Vt, bv, Dq, Dq, Sq, 0, (long long)Sq * Dq, (long long)Uq * Sq, Dq, 0, 0);

  // Sc[b][i][j] = Qb_b[i] . Kb_b[j]  (bf16 out, skip fully-masked tiles)
  gemm_tn<1, 0><<<dim3(Sq / BM, Sq / BN, Bq), 256, 0, stream>>>(
      Qb, Kb, Sc, nullptr, Uq, Uq, Sq, (long long)Sq * Uq, (long long)Sq * Uq,
      (long long)Sq * Sq, Uq, 1, 0);

  softmax_causal<<<Bq * Sq, 256, 0, stream>>>(Sc);

  // Out[b][i][u] = sum_j alpha[b][i][j] * Vt[b][u][j]  (causal K-limit)
  gemm_tn<0, 0><<<dim3(Sq / BM, Uq / BN, Bq), 256, 0, stream>>>(
      (const bf16*)Sc, Vt, out, nullptr, Sq, Sq, Uq, (long long)Sq * Sq,
      (long long)Uq * Sq, (long long)Sq * Uq, Sq, 0, 1);

  (void)in_sizes; (void)n_in; (void)ws_size;
}

// Round 3
// 601.821 us; speedup vs baseline: 1.0795x; 1.0795x over previous
//
#include <hip/hip_runtime.h>

// B=8, S=2048, D=1024, U=1024, fp32 in/out, bf16-grade tolerance.
// Pipeline (bf16 MFMA TN GEMMs, double-buffered LDS with fine-grained vmcnt):
//   WqmT = metricT @ WqB            (metric folded into Wq)
//   Qb   = X1b @ WqmT + bqm  -> d_out[0:33.5MB]     (scratch in d_out)
//   Kb   = X2b @ WkT  + bk   -> d_out[33.5:67MB]
//   Vt_b = WvT @ X2b_b^T + bv  [U][S] per batch
//   Sc_b = Qb_b @ Kb_b^T  bf16, aliased over X1b+X2b (dead), causal tile skip
//   alpha = softmax(Sc/32) bf16 in place
//   Out_b = alpha_b @ Vt_b^T -> d_out (fp32), causal K-limit, longest-first
// Peak d_ws: 111,153,152 B.

#define Bq 8
#define Sq 2048
#define Dq 1024
#define Uq 1024

typedef __bf16 bf16;
typedef __bf16 bf16x8 __attribute__((ext_vector_type(8)));
typedef float f32x4 __attribute__((ext_vector_type(4)));
typedef unsigned short u16;
typedef unsigned int u32;

__device__ __forceinline__ u16 f2bf(float f) {
  u32 u = __builtin_bit_cast(u32, f);
  u32 r = u + 0x7fffu + ((u >> 16) & 1u);
  return (u16)(r >> 16);
}
__device__ __forceinline__ float bf2f(u32 h) {
  return __builtin_bit_cast(float, h << 16);
}

__device__ __forceinline__ void gl_lds16(const void* g, void* l) {
  __builtin_amdgcn_global_load_lds(
      (const __attribute__((address_space(1))) u32*)g,
      (__attribute__((address_space(3))) u32*)l, 16, 0, 0);
}

// ---------------- converts ----------------

// z selects (X1 -> X1b) or (X2 -> X2b)
__global__ __launch_bounds__(256) void cvt_x(const float* __restrict__ x1,
                                             const float* __restrict__ x2,
                                             u16* __restrict__ o1,
                                             u16* __restrict__ o2, int n4) {
  int idx = blockIdx.x * 256 + threadIdx.x;
  if (idx >= n4) return;
  const float* in = blockIdx.y ? x2 : x1;
  u16* out = blockIdx.y ? o2 : o1;
  float4 v = ((const float4*)in)[idx];
  ushort4 o;
  o.x = f2bf(v.x); o.y = f2bf(v.y); o.z = f2bf(v.z); o.w = f2bf(v.w);
  ((ushort4*)out)[idx] = o;
}

__global__ __launch_bounds__(256) void cvt_bf16(const float* __restrict__ in,
                                                u16* __restrict__ out, int n4) {
  int idx = blockIdx.x * 256 + threadIdx.x;
  if (idx >= n4) return;
  float4 v = ((const float4*)in)[idx];
  ushort4 o;
  o.x = f2bf(v.x); o.y = f2bf(v.y); o.z = f2bf(v.z); o.w = f2bf(v.w);
  ((ushort4*)out)[idx] = o;
}

// out[x][y] = bf16(in[y][x]), 1024x1024; z picks among 3 (src,dst) pairs
__global__ __launch_bounds__(256) void transpose_cvt3(
    const float* __restrict__ s0, u16* __restrict__ d0,
    const float* __restrict__ s1, u16* __restrict__ d1,
    const float* __restrict__ s2, u16* __restrict__ d2) {
  __shared__ float tile[32][33];
  const float* in = (blockIdx.z == 0) ? s0 : (blockIdx.z == 1) ? s1 : s2;
  u16* out = (blockIdx.z == 0) ? d0 : (blockIdx.z == 1) ? d1 : d2;
  const int N = 1024;
  int tx = threadIdx.x & 31, ty = threadIdx.x >> 5;  // 32 x 8
  int x0 = blockIdx.x * 32, y0 = blockIdx.y * 32;
#pragma unroll
  for (int r = 0; r < 32; r += 8)
    tile[ty + r][tx] = in[(size_t)(y0 + ty + r) * N + x0 + tx];
  __syncthreads();
#pragma unroll
  for (int r = 0; r < 32; r += 8)
    out[(size_t)(x0 + ty + r) * N + y0 + tx] = f2bf(tile[tx][ty + r]);
}

__global__ __launch_bounds__(256) void bqm_kernel(const float* __restrict__ bq,
                                                  const float* __restrict__ metric,
                                                  float* __restrict__ bqm) {
  int v = blockIdx.x * 256 + threadIdx.x;
  float s = 0.f;
  for (int u = 0; u < Uq; ++u) s += bq[u] * metric[(size_t)u * Uq + v];
  bqm[v] = s;
}

__global__ __launch_bounds__(256) void fill_zero(float4* __restrict__ p, int n4) {
  int i = blockIdx.x * 256 + threadIdx.x;
  if (i < n4) p[i] = float4{0.f, 0.f, 0.f, 0.f};
}

// ---------------- TN bf16 MFMA GEMM, double-buffered ----------------
// C[m][n] = sum_k A[m*lda+k] * B[n*ldb+k] (+ bias)
// BIAS: 0 none, 1 per-col(n), 2 per-row(m). OUT_BF16: 1 -> u16 bf16 out.
#define BM 128
#define BN 128
#define BK 32

template <int OUT_BF16, int BIAS>
__global__ __launch_bounds__(256) void gemm_tn(
    const bf16* __restrict__ A, const bf16* __restrict__ B, void* __restrict__ Cv,
    const float* __restrict__ bias, int lda, int ldb, int ldc,
    long long sA, long long sB, long long sC, int K,
    int causal_skip, int causal_klimit) {
  __shared__ __align__(16) bf16 lA[2][BM * BK];
  __shared__ __align__(16) bf16 lB[2][BN * BK];
  int bx = causal_klimit ? (gridDim.x - 1 - blockIdx.x) : blockIdx.x;
  int m0 = bx * BM, n0 = blockIdx.y * BN;
  if (causal_skip && n0 > m0 + BM - 1) return;
  long long b = blockIdx.z;
  A += b * sA;
  B += b * sB;
  int t = threadIdx.x;
  int w = t >> 6, l = t & 63;
  int wr = (w >> 1) * 64, wc = (w & 1) * 64;
  int Kend = causal_klimit ? min(K, m0 + BM) : K;
  int nk = Kend / BK;

  f32x4 acc[4][4] = {};
  int rowA = t >> 2, kc = (t & 3) * 8;  // 64B LDS rows, 4 x 16B chunks per row
  int lm = l & 15, q = l >> 4;

  const bf16* gA = A + (long long)(m0 + rowA) * lda + kc;
  const bf16* gB = B + (long long)(n0 + rowA) * ldb + kc;
  long long a64 = (long long)64 * lda, b64 = (long long)64 * ldb;

  auto stage = [&](int kt, int buf) {
    int k0 = kt * BK;
    char* dA = (char*)lA[buf] + w * 1024;
    char* dB = (char*)lB[buf] + w * 1024;
    gl_lds16(gA + k0, dA);
    gl_lds16(gA + k0 + a64, dA + 4096);
    gl_lds16(gB + k0, dB);
    gl_lds16(gB + k0 + b64, dB + 4096);
  };

  stage(0, 0);
  for (int kt = 0; kt < nk; ++kt) {
    int cur = kt & 1;
    if (kt + 1 < nk) {
      stage(kt + 1, cur ^ 1);
      // wait only the OLDER 4 loads (stage kt); prefetch stays in flight
      asm volatile("s_waitcnt vmcnt(4)\n\ts_barrier" ::: "memory");
    } else {
      asm volatile("s_waitcnt vmcnt(0)\n\ts_barrier" ::: "memory");
    }
    bf16x8 af[4], bfr[4];
#pragma unroll
    for (int i = 0; i < 4; ++i)
      af[i] = *(const bf16x8*)&lA[cur][(wr + i * 16 + lm) * BK + q * 8];
#pragma unroll
    for (int i = 0; i < 4; ++i)
      bfr[i] = *(const bf16x8*)&lB[cur][(wc + i * 16 + lm) * BK + q * 8];
#pragma unroll
    for (int i = 0; i < 4; ++i)
#pragma unroll
      for (int j = 0; j < 4; ++j)
        acc[i][j] = __builtin_amdgcn_mfma_f32_16x16x32_bf16(af[i], bfr[j], acc[i][j], 0, 0, 0);
    // protect lA/lB[cur] from being overwritten by stage kt+2 (no vmcnt drain:
    // each wave's ds_reads completed before its MFMAs consumed them)
    asm volatile("s_barrier" ::: "memory");
  }

  // epilogue: C row = wr + i*16 + q*4 + r ; col = wc + j*16 + lm
  char* Cb = (char*)Cv + (OUT_BF16 ? b * sC * 2 : b * sC * 4);
#pragma unroll
  for (int i = 0; i < 4; ++i) {
#pragma unroll
    for (int j = 0; j < 4; ++j) {
      int col = n0 + wc + j * 16 + lm;
      float bc = (BIAS == 1) ? bias[col] : 0.f;
#pragma unroll
      for (int r = 0; r < 4; ++r) {
        int row = m0 + wr + i * 16 + q * 4 + r;
        float v = acc[i][j][r] + bc;
        if (BIAS == 2) v += bias[row];
        size_t idx = (size_t)row * ldc + col;
        if (OUT_BF16)
          ((u16*)Cb)[idx] = f2bf(v);
        else
          ((float*)Cb)[idx] = v;
      }
    }
  }
}

// ---------------- causal softmax (bf16 in place) ----------------
__global__ __launch_bounds__(256) void softmax_causal(u16* __restrict__ sc) {
  __shared__ __align__(16) float sm[Sq];
  __shared__ float red[8];
  int gr = blockIdx.x;
  int i = gr & (Sq - 1);
  u16* rowp = sc + (size_t)gr * Sq;
  int t = threadIdx.x;
  uint4 pk = ((const uint4*)rowp)[t];  // 8 bf16
  float4 lo, hi;
  lo.x = bf2f(pk.x & 0xffffu); lo.y = bf2f(pk.x >> 16);
  lo.z = bf2f(pk.y & 0xffffu); lo.w = bf2f(pk.y >> 16);
  hi.x = bf2f(pk.z & 0xffffu); hi.y = bf2f(pk.z >> 16);
  hi.z = bf2f(pk.w & 0xffffu); hi.w = bf2f(pk.w >> 16);
  ((float4*)sm)[2 * t] = lo;
  ((float4*)sm)[2 * t + 1] = hi;
  __syncthreads();
  int nv = i + 1;
  const float scl = 0.03125f;  // 1/sqrt(U) = 1/32
  float m = -1e30f;
  for (int j = t; j < nv; j += 256) m = fmaxf(m, sm[j]);
#pragma unroll
  for (int o = 32; o; o >>= 1) m = fmaxf(m, __shfl_xor(m, o));
  if ((t & 63) == 0) red[t >> 6] = m;
  __syncthreads();
  m = fmaxf(fmaxf(red[0], red[1]), fmaxf(red[2], red[3])) * scl;
  float sum = 0.f;
  for (int j = t; j < nv; j += 256) sum += __expf(sm[j] * scl - m);
#pragma unroll
  for (int o = 32; o; o >>= 1) sum += __shfl_xor(sum, o);
  if ((t & 63) == 0) red[4 + (t >> 6)] = sum;
  __syncthreads();
  float rinv = 1.0f / (red[4] + red[5] + red[6] + red[7]);
  int j0 = t * 8;
  u16 ov[8];
#pragma unroll
  for (int k = 0; k < 8; ++k)
    ov[k] = (j0 + k < nv) ? f2bf(__expf(sm[j0 + k] * scl - m) * rinv) : (u16)0;
  uint4 po;
  po.x = (u32)ov[0] | ((u32)ov[1] << 16);
  po.y = (u32)ov[2] | ((u32)ov[3] << 16);
  po.z = (u32)ov[4] | ((u32)ov[5] << 16);
  po.w = (u32)ov[6] | ((u32)ov[7] << 16);
  ((uint4*)rowp)[t] = po;
}

// ---------------- launch ----------------

extern "C" void kernel_launch(void* const* d_in, const int* in_sizes, int n_in,
                              void* d_out, int out_size, void* d_ws, size_t ws_size,
                              hipStream_t stream) {
  const float* X1 = (const float*)d_in[0];
  const float* X2 = (const float*)d_in[1];
  const float* Wq = (const float*)d_in[2];
  const float* bq = (const float*)d_in[3];
  const float* Wk = (const float*)d_in[4];
  const float* bk = (const float*)d_in[5];
  const float* Wv = (const float*)d_in[6];
  const float* bv = (const float*)d_in[7];
  const float* metric = (const float*)d_in[8];
  float* out = (float*)d_out;

  const size_t XB = (size_t)Bq * Sq * Dq * 2;  // 33,554,432 B
  const size_t WB = (size_t)Dq * Uq * 2;       // 2,097,152 B
  const size_t NEED = 3 * XB + 5 * WB + 4096;  // 111,153,152 B

  if (ws_size < NEED) {
    fill_zero<<<(out_size / 4 + 255) / 256, 256, 0, stream>>>((float4*)d_out, out_size / 4);
    return;
  }

  char* ws = (char*)d_ws;
  bf16* X1b = (bf16*)(ws);
  bf16* X2b = (bf16*)(ws + XB);
  bf16* Vt = (bf16*)(ws + 2 * XB);
  bf16* WqB = (bf16*)(ws + 3 * XB);
  bf16* metT = (bf16*)(ws + 3 * XB + WB);
  bf16* WkT = (bf16*)(ws + 3 * XB + 2 * WB);
  bf16* WvT = (bf16*)(ws + 3 * XB + 3 * WB);
  bf16* WqmT = (bf16*)(ws + 3 * XB + 4 * WB);
  float* bqm = (float*)(ws + 3 * XB + 5 * WB);
  u16* Sc = (u16*)ws;  // bf16 scores alias X1b+X2b (dead by then)
  bf16* Qb = (bf16*)d_out;                          // scratch in d_out
  bf16* Kb = (bf16*)d_out + (size_t)Bq * Sq * Uq;   // second half of d_out

  // converts
  int nx4 = Bq * Sq * Dq / 4;
  cvt_x<<<dim3((nx4 + 255) / 256, 2), 256, 0, stream>>>(X1, X2, (u16*)X1b, (u16*)X2b, nx4);
  cvt_bf16<<<(Dq * Uq / 4 + 255) / 256, 256, 0, stream>>>(Wq, (u16*)WqB, Dq * Uq / 4);
  transpose_cvt3<<<dim3(32, 32, 3), 256, 0, stream>>>(
      metric, (u16*)metT, Wk, (u16*)WkT, Wv, (u16*)WvT);
  bqm_kernel<<<Uq / 256, 256, 0, stream>>>(bq, metric, bqm);

  // WqmT[v][d] = sum_u metT[v][u] * WqB[d][u]
  gemm_tn<1, 0><<<dim3(Uq / BM, Dq / BN, 1), 256, 0, stream>>>(
      metT, WqB, WqmT, nullptr, Uq, Uq, Dq, 0, 0, 0, Uq, 0, 0);

  const int MQ = Bq * Sq;  // 16384
  // Qb = X1b @ WqmT^T + bqm   -> d_out scratch
  gemm_tn<1, 1><<<dim3(MQ / BM, Uq / BN, 1), 256, 0, stream>>>(
      X1b, WqmT, Qb, bqm, Dq, Dq, Uq, 0, 0, 0, Dq, 0, 0);
  // Kb = X2b @ WkT + bk       -> d_out scratch
  gemm_tn<1, 1><<<dim3(MQ / BM, Uq / BN, 1), 256, 0, stream>>>(
      X2b, WkT, Kb, bk, Dq, Dq, Uq, 0, 0, 0, Dq, 0, 0);
  // Vt[b][u][j] = sum_d WvT[u][d] * X2b[b][j][d] + bv[u]
  gemm_tn<1, 2><<<dim3(Uq / BM, Sq / BN, Bq), 256, 0, stream>>>(
      WvT, X2b, Vt, bv, Dq, Dq, Sq, 0, (long long)Sq * Dq, (long long)Uq * Sq, Dq, 0, 0);

  // Sc[b][i][j] = Qb_b[i] . Kb_b[j]  (bf16 out, skip fully-masked tiles)
  gemm_tn<1, 0><<<dim3(Sq / BM, Sq / BN, Bq), 256, 0, stream>>>(
      Qb, Kb, Sc, nullptr, Uq, Uq, Sq, (long long)Sq * Uq, (long long)Sq * Uq,
      (long long)Sq * Sq, Uq, 1, 0);

  softmax_causal<<<Bq * Sq, 256, 0, stream>>>(Sc);

  // Out[b][i][u] = sum_j alpha[b][i][j] * Vt[b][u][j]  (causal K-limit, longest-first)
  gemm_tn<0, 0><<<dim3(Sq / BM, Uq / BN, Bq), 256, 0, stream>>>(
      (const bf16*)Sc, Vt, out, nullptr, Sq, Sq, Uq, (long long)Sq * Sq,
      (long long)Uq * Sq, (long long)Sq * Uq, Sq, 0, 1);

  (void)in_sizes; (void)n_in; (void)ws_size;
}

// Round 5
// 600.940 us; speedup vs baseline: 1.0810x; 1.0015x over previous
//
#include <hip/hip_runtime.h>

// B=8, S=2048, D=1024, U=1024, fp32 in/out, bf16-grade tolerance.
// Pipeline (bf16 MFMA TN GEMMs, 3-buffer LDS, prefetch distance 2, vmcnt(8)):
//   WqmT = metricT @ WqB            (metric folded into Wq)
//   Qb   = X1b @ WqmT + bqm  -> d_out[0:33.5MB]     (scratch in d_out)
//   Kb   = X2b @ WkT  + bk   -> d_out[33.5:67MB]
//   Vt_b = WvT @ X2b_b^T + bv  [U][S] per batch
//   Sc_b = Qb_b @ Kb_b^T  bf16, aliased over X1b+X2b (dead), causal tile skip
//   alpha = softmax(Sc/32) bf16 in place
//   Out_b = alpha_b @ Vt_b^T -> d_out (fp32), causal K-limit, longest-first
// Peak d_ws: 111,153,152 B.
// R4 bug fixed: prefetch buffer index used (kt+2-3), not a modulo -> LDS
// overflow into lB for kt>=4. Now rotates pb = cur+2 (mod 3).

#define Bq 8
#define Sq 2048
#define Dq 1024
#define Uq 1024

typedef __bf16 bf16;
typedef __bf16 bf16x8 __attribute__((ext_vector_type(8)));
typedef float f32x4 __attribute__((ext_vector_type(4)));
typedef unsigned short u16;
typedef unsigned int u32;

__device__ __forceinline__ u16 f2bf(float f) {
  u32 u = __builtin_bit_cast(u32, f);
  u32 r = u + 0x7fffu + ((u >> 16) & 1u);
  return (u16)(r >> 16);
}
__device__ __forceinline__ float bf2f(u32 h) {
  return __builtin_bit_cast(float, h << 16);
}

__device__ __forceinline__ void gl_lds16(const void* g, void* l) {
  __builtin_amdgcn_global_load_lds(
      (const __attribute__((address_space(1))) u32*)g,
      (__attribute__((address_space(3))) u32*)l, 16, 0, 0);
}

// ---------------- converts ----------------

__global__ __launch_bounds__(256) void cvt_x(const float* __restrict__ x1,
                                             const float* __restrict__ x2,
                                             u16* __restrict__ o1,
                                             u16* __restrict__ o2, int n4) {
  int idx = blockIdx.x * 256 + threadIdx.x;
  if (idx >= n4) return;
  const float* in = blockIdx.y ? x2 : x1;
  u16* out = blockIdx.y ? o2 : o1;
  float4 v = ((const float4*)in)[idx];
  ushort4 o;
  o.x = f2bf(v.x); o.y = f2bf(v.y); o.z = f2bf(v.z); o.w = f2bf(v.w);
  ((ushort4*)out)[idx] = o;
}

__global__ __launch_bounds__(256) void cvt_bf16(const float* __restrict__ in,
                                                u16* __restrict__ out, int n4) {
  int idx = blockIdx.x * 256 + threadIdx.x;
  if (idx >= n4) return;
  float4 v = ((const float4*)in)[idx];
  ushort4 o;
  o.x = f2bf(v.x); o.y = f2bf(v.y); o.z = f2bf(v.z); o.w = f2bf(v.w);
  ((ushort4*)out)[idx] = o;
}

// out[x][y] = bf16(in[y][x]), 1024x1024; z picks among 3 (src,dst) pairs
__global__ __launch_bounds__(256) void transpose_cvt3(
    const float* __restrict__ s0, u16* __restrict__ d0,
    const float* __restrict__ s1, u16* __restrict__ d1,
    const float* __restrict__ s2, u16* __restrict__ d2) {
  __shared__ float tile[32][33];
  const float* in = (blockIdx.z == 0) ? s0 : (blockIdx.z == 1) ? s1 : s2;
  u16* out = (blockIdx.z == 0) ? d0 : (blockIdx.z == 1) ? d1 : d2;
  const int N = 1024;
  int tx = threadIdx.x & 31, ty = threadIdx.x >> 5;  // 32 x 8
  int x0 = blockIdx.x * 32, y0 = blockIdx.y * 32;
#pragma unroll
  for (int r = 0; r < 32; r += 8)
    tile[ty + r][tx] = in[(size_t)(y0 + ty + r) * N + x0 + tx];
  __syncthreads();
#pragma unroll
  for (int r = 0; r < 32; r += 8)
    out[(size_t)(x0 + ty + r) * N + y0 + tx] = f2bf(tile[tx][ty + r]);
}

__global__ __launch_bounds__(256) void bqm_kernel(const float* __restrict__ bq,
                                                  const float* __restrict__ metric,
                                                  float* __restrict__ bqm) {
  int v = blockIdx.x * 256 + threadIdx.x;
  float s = 0.f;
  for (int u = 0; u < Uq; ++u) s += bq[u] * metric[(size_t)u * Uq + v];
  bqm[v] = s;
}

__global__ __launch_bounds__(256) void fill_zero(float4* __restrict__ p, int n4) {
  int i = blockIdx.x * 256 + threadIdx.x;
  if (i < n4) p[i] = float4{0.f, 0.f, 0.f, 0.f};
}

// ---------------- TN bf16 MFMA GEMM, 3-buffer prefetch-2 pipeline ----------------
// C[m][n] = sum_k A[m*lda+k] * B[n*ldb+k] (+ bias)
// BIAS: 0 none, 1 per-col(n), 2 per-row(m). OUT_BF16: 1 -> u16 bf16 out.
#define BM 128
#define BN 128
#define BK 32

template <int OUT_BF16, int BIAS>
__global__ __launch_bounds__(256) void gemm_tn(
    const bf16* __restrict__ A, const bf16* __restrict__ B, void* __restrict__ Cv,
    const float* __restrict__ bias, int lda, int ldb, int ldc,
    long long sA, long long sB, long long sC, int K,
    int causal_skip, int causal_klimit) {
  // 3 stages x (A 8KB + B 8KB) = 48 KB  -> 3 blocks/CU
  __shared__ __align__(16) bf16 lA[3][BM * BK];
  __shared__ __align__(16) bf16 lB[3][BN * BK];
  int bx = causal_klimit ? (gridDim.x - 1 - blockIdx.x) : blockIdx.x;
  int m0 = bx * BM, n0 = blockIdx.y * BN;
  if (causal_skip && n0 > m0 + BM - 1) return;
  long long b = blockIdx.z;
  A += b * sA;
  B += b * sB;
  int t = threadIdx.x;
  int w = t >> 6, l = t & 63;
  int wr = (w >> 1) * 64, wc = (w & 1) * 64;
  int Kend = causal_klimit ? min(K, m0 + BM) : K;
  int nk = Kend / BK;  // >= 4 for all our shapes

  f32x4 acc[4][4] = {};
  int rowA = t >> 2, kc = (t & 3) * 8;  // 64B LDS rows, 4 x 16B chunks per row
  int lm = l & 15, q = l >> 4;

  const bf16* gA = A + (long long)(m0 + rowA) * lda + kc;
  const bf16* gB = B + (long long)(n0 + rowA) * ldb + kc;
  long long a64 = (long long)64 * lda, b64 = (long long)64 * ldb;

  auto stage = [&](int kt, int buf) {
    int k0 = kt * BK;
    char* dA = (char*)lA[buf] + w * 1024;
    char* dB = (char*)lB[buf] + w * 1024;
    gl_lds16(gA + k0, dA);
    gl_lds16(gA + k0 + a64, dA + 4096);
    gl_lds16(gB + k0, dB);
    gl_lds16(gB + k0 + b64, dB + 4096);
  };

  stage(0, 0);
  stage(1, 1);
  int cur = 0;
  for (int kt = 0; kt < nk; ++kt) {
    if (kt + 2 < nk) {
      // prefetch buffer = (cur+2) mod 3 == (kt+2) mod 3; its previous readers
      // (compute kt-1) finished before the previous iteration's end barrier.
      int pb = cur + 2;
      if (pb >= 3) pb -= 3;
      stage(kt + 2, pb);
      // drain only stage kt's 4 loads; stages kt+1, kt+2 (8) stay in flight
      asm volatile("s_waitcnt vmcnt(8)\n\ts_barrier" ::: "memory");
    } else if (kt + 1 < nk) {
      asm volatile("s_waitcnt vmcnt(4)\n\ts_barrier" ::: "memory");
    } else {
      asm volatile("s_waitcnt vmcnt(0)\n\ts_barrier" ::: "memory");
    }
    bf16x8 af[4], bfr[4];
#pragma unroll
    for (int i = 0; i < 4; ++i)
      af[i] = *(const bf16x8*)&lA[cur][(wr + i * 16 + lm) * BK + q * 8];
#pragma unroll
    for (int i = 0; i < 4; ++i)
      bfr[i] = *(const bf16x8*)&lB[cur][(wc + i * 16 + lm) * BK + q * 8];
#pragma unroll
    for (int i = 0; i < 4; ++i)
#pragma unroll
      for (int j = 0; j < 4; ++j)
        acc[i][j] = __builtin_amdgcn_mfma_f32_16x16x32_bf16(af[i], bfr[j], acc[i][j], 0, 0, 0);
    // all waves done reading lA/lB[cur] before next iter's stage overwrites it
    asm volatile("s_barrier" ::: "memory");
    cur = (cur == 2) ? 0 : cur + 1;
  }

  // epilogue: C row = wr + i*16 + q*4 + r ; col = wc + j*16 + lm
  char* Cb = (char*)Cv + (OUT_BF16 ? b * sC * 2 : b * sC * 4);
#pragma unroll
  for (int i = 0; i < 4; ++i) {
#pragma unroll
    for (int j = 0; j < 4; ++j) {
      int col = n0 + wc + j * 16 + lm;
      float bc = (BIAS == 1) ? bias[col] : 0.f;
#pragma unroll
      for (int r = 0; r < 4; ++r) {
        int row = m0 + wr + i * 16 + q * 4 + r;
        float v = acc[i][j][r] + bc;
        if (BIAS == 2) v += bias[row];
        size_t idx = (size_t)row * ldc + col;
        if (OUT_BF16)
          ((u16*)Cb)[idx] = f2bf(v);
        else
          ((float*)Cb)[idx] = v;
      }
    }
  }
}

// ---------------- causal softmax (bf16 in place) ----------------
__global__ __launch_bounds__(256) void softmax_causal(u16* __restrict__ sc) {
  __shared__ __align__(16) float sm[Sq];
  __shared__ float red[8];
  int gr = blockIdx.x;
  int i = gr & (Sq - 1);
  u16* rowp = sc + (size_t)gr * Sq;
  int t = threadIdx.x;
  uint4 pk = ((const uint4*)rowp)[t];  // 8 bf16
  float4 lo, hi;
  lo.x = bf2f(pk.x & 0xffffu); lo.y = bf2f(pk.x >> 16);
  lo.z = bf2f(pk.y & 0xffffu); lo.w = bf2f(pk.y >> 16);
  hi.x = bf2f(pk.z & 0xffffu); hi.y = bf2f(pk.z >> 16);
  hi.z = bf2f(pk.w & 0xffffu); hi.w = bf2f(pk.w >> 16);
  ((float4*)sm)[2 * t] = lo;
  ((float4*)sm)[2 * t + 1] = hi;
  __syncthreads();
  int nv = i + 1;
  const float scl = 0.03125f;  // 1/sqrt(U) = 1/32
  float m = -1e30f;
  for (int j = t; j < nv; j += 256) m = fmaxf(m, sm[j]);
#pragma unroll
  for (int o = 32; o; o >>= 1) m = fmaxf(m, __shfl_xor(m, o));
  if ((t & 63) == 0) red[t >> 6] = m;
  __syncthreads();
  m = fmaxf(fmaxf(red[0], red[1]), fmaxf(red[2], red[3])) * scl;
  float sum = 0.f;
  for (int j = t; j < nv; j += 256) sum += __expf(sm[j] * scl - m);
#pragma unroll
  for (int o = 32; o; o >>= 1) sum += __shfl_xor(sum, o);
  if ((t & 63) == 0) red[4 + (t >> 6)] = sum;
  __syncthreads();
  float rinv = 1.0f / (red[4] + red[5] + red[6] + red[7]);
  int j0 = t * 8;
  u16 ov[8];
#pragma unroll
  for (int k = 0; k < 8; ++k)
    ov[k] = (j0 + k < nv) ? f2bf(__expf(sm[j0 + k] * scl - m) * rinv) : (u16)0;
  uint4 po;
  po.x = (u32)ov[0] | ((u32)ov[1] << 16);
  po.y = (u32)ov[2] | ((u32)ov[3] << 16);
  po.z = (u32)ov[4] | ((u32)ov[5] << 16);
  po.w = (u32)ov[6] | ((u32)ov[7] << 16);
  ((uint4*)rowp)[t] = po;
}

// ---------------- launch ----------------

extern "C" void kernel_launch(void* const* d_in, const int* in_sizes, int n_in,
                              void* d_out, int out_size, void* d_ws, size_t ws_size,
                              hipStream_t stream) {
  const float* X1 = (const float*)d_in[0];
  const float* X2 = (const float*)d_in[1];
  const float* Wq = (const float*)d_in[2];
  const float* bq = (const float*)d_in[3];
  const float* Wk = (const float*)d_in[4];
  const float* bk = (const float*)d_in[5];
  const float* Wv = (const float*)d_in[6];
  const float* bv = (const float*)d_in[7];
  const float* metric = (const float*)d_in[8];
  float* out = (float*)d_out;

  const size_t XB = (size_t)Bq * Sq * Dq * 2;  // 33,554,432 B
  const size_t WB = (size_t)Dq * Uq * 2;       // 2,097,152 B
  const size_t NEED = 3 * XB + 5 * WB + 4096;  // 111,153,152 B

  if (ws_size < NEED) {
    fill_zero<<<(out_size / 4 + 255) / 256, 256, 0, stream>>>((float4*)d_out, out_size / 4);
    return;
  }

  char* ws = (char*)d_ws;
  bf16* X1b = (bf16*)(ws);
  bf16* X2b = (bf16*)(ws + XB);
  bf16* Vt = (bf16*)(ws + 2 * XB);
  bf16* WqB = (bf16*)(ws + 3 * XB);
  bf16* metT = (bf16*)(ws + 3 * XB + WB);
  bf16* WkT = (bf16*)(ws + 3 * XB + 2 * WB);
  bf16* WvT = (bf16*)(ws + 3 * XB + 3 * WB);
  bf16* WqmT = (bf16*)(ws + 3 * XB + 4 * WB);
  float* bqm = (float*)(ws + 3 * XB + 5 * WB);
  u16* Sc = (u16*)ws;  // bf16 scores alias X1b+X2b (dead by then)
  bf16* Qb = (bf16*)d_out;                          // scratch in d_out
  bf16* Kb = (bf16*)d_out + (size_t)Bq * Sq * Uq;   // second half of d_out

  // converts
  int nx4 = Bq * Sq * Dq / 4;
  cvt_x<<<dim3((nx4 + 255) / 256, 2), 256, 0, stream>>>(X1, X2, (u16*)X1b, (u16*)X2b, nx4);
  cvt_bf16<<<(Dq * Uq / 4 + 255) / 256, 256, 0, stream>>>(Wq, (u16*)WqB, Dq * Uq / 4);
  transpose_cvt3<<<dim3(32, 32, 3), 256, 0, stream>>>(
      metric, (u16*)metT, Wk, (u16*)WkT, Wv, (u16*)WvT);
  bqm_kernel<<<Uq / 256, 256, 0, stream>>>(bq, metric, bqm);

  // WqmT[v][d] = sum_u metT[v][u] * WqB[d][u]
  gemm_tn<1, 0><<<dim3(Uq / BM, Dq / BN, 1), 256, 0, stream>>>(
      metT, WqB, WqmT, nullptr, Uq, Uq, Dq, 0, 0, 0, Uq, 0, 0);

  const int MQ = Bq * Sq;  // 16384
  // Qb = X1b @ WqmT^T + bqm   -> d_out scratch
  gemm_tn<1, 1><<<dim3(MQ / BM, Uq / BN, 1), 256, 0, stream>>>(
      X1b, WqmT, Qb, bqm, Dq, Dq, Uq, 0, 0, 0, Dq, 0, 0);
  // Kb = X2b @ WkT + bk       -> d_out scratch
  gemm_tn<1, 1><<<dim3(MQ / BM, Uq / BN, 1), 256, 0, stream>>>(
      X2b, WkT, Kb, bk, Dq, Dq, Uq, 0, 0, 0, Dq, 0, 0);
  // Vt[b][u][j] = sum_d WvT[u][d] * X2b[b][j][d] + bv[u]
  gemm_tn<1, 2><<<dim3(Uq / BM, Sq / BN, Bq), 256, 0, stream>>>(
      WvT, X2b, Vt, bv, Dq, Dq, Sq, 0, (long long)Sq * Dq, (long long)Uq * Sq, Dq, 0, 0);

  // Sc[b][i][j] = Qb_b[i] . Kb_b[j]  (bf16 out, skip fully-masked tiles)
  gemm_tn<1, 0><<<dim3(Sq / BM, Sq / BN, Bq), 256, 0, stream>>>(
      Qb, Kb, Sc, nullptr, Uq, Uq, Sq, (long long)Sq * Uq, (long long)Sq * Uq,
      (long long)Sq * Sq, Uq, 1, 0);

  softmax_causal<<<Bq * Sq, 256, 0, stream>>>(Sc);

  // Out[b][i][u] = sum_j alpha[b][i][j] * Vt[b][u][j]  (causal K-limit, longest-first)
  gemm_tn<0, 0><<<dim3(Sq / BM, Uq / BN, Bq), 256, 0, stream>>>(
      (const bf16*)Sc, Vt, out, nullptr, Sq, Sq, Uq, (long long)Sq * Sq,
      (long long)Uq * Sq, (long long)Sq * Uq, Sq, 0, 1);

  (void)in_sizes; (void)n_in; (void)ws_size;
}